// Round 14
// baseline (224.292 us; speedup 1.0000x reference)
//
#include <hip/hip_runtime.h>
#include <hip/hip_bf16.h>
#include <cstdint>

typedef __attribute__((ext_vector_type(4))) float f32x4;
typedef __attribute__((ext_vector_type(16))) float f32x16;
typedef __attribute__((ext_vector_type(8))) short s16x8;
typedef __attribute__((ext_vector_type(4))) unsigned u32x4;
typedef unsigned short u16;

#define B_  4
#define N_  1024
#define D_  1024
#define H_  16
#define DH_ 64
#define M_  4096      // B_*N_
#define SIXD 6144

#define WAITV(n) asm volatile("s_waitcnt vmcnt(" #n ")" ::: "memory")

__device__ __forceinline__ u16 f2bf(float f) {
    unsigned u = __builtin_bit_cast(unsigned, f);
    unsigned r = (u + 0x7fffu + ((u >> 16) & 1u)) >> 16;
    return (u16)r;
}

__device__ __forceinline__ unsigned cvtpk(float a, float b) {
    unsigned r;
    asm("v_cvt_pk_bf16_f32 %0, %1, %2" : "=v"(r) : "v"(a), "v"(b));
    return r;
}

__device__ __forceinline__ void gload16(const void* g, void* l) {
    __builtin_amdgcn_global_load_lds((const __attribute__((address_space(1))) void*)g,
                                     (__attribute__((address_space(3))) void*)l,
                                     16, 0, 0);
}

// ------- fused prep: modk K-split partials (first, latency) + 64x64 transposes ----
__global__ __launch_bounds__(256) void prep_all(const float* __restrict__ Wq,
                                                const float* __restrict__ Wkv,
                                                const float* __restrict__ Wo,
                                                const float* __restrict__ W1,
                                                const float* __restrict__ W2,
                                                const float* __restrict__ c,
                                                const float* __restrict__ Wada,
                                                u16* __restrict__ wqkvT,
                                                u16* __restrict__ woT,
                                                u16* __restrict__ w1T,
                                                u16* __restrict__ w2T,
                                                float* __restrict__ modp) {
    int id = blockIdx.x;
    int tid = threadIdx.x;
    if (id < 768) {
        __shared__ float sc[128];
        int colblk = id % 24, b = (id / 24) & 3, ks = id / 96;
        int col = colblk * 256 + tid;
        int k0 = ks * 128;
        if (tid < 128) {
            float v = c[b * D_ + k0 + tid];
            sc[tid] = v / (1.f + __expf(-v));
        }
        __syncthreads();
        float a0 = 0.f, a1 = 0.f, a2 = 0.f, a3 = 0.f;
#pragma unroll 4
        for (int k = 0; k < 128; k += 4) {
            a0 = fmaf(sc[k + 0], Wada[(size_t)(k0 + k + 0) * SIXD + col], a0);
            a1 = fmaf(sc[k + 1], Wada[(size_t)(k0 + k + 1) * SIXD + col], a1);
            a2 = fmaf(sc[k + 2], Wada[(size_t)(k0 + k + 2) * SIXD + col], a2);
            a3 = fmaf(sc[k + 3], Wada[(size_t)(k0 + k + 3) * SIXD + col], a3);
        }
        modp[(size_t)(ks * 4 + b) * SIXD + col] = (a0 + a1) + (a2 + a3);
        return;
    }
    int t_ = id - 768;
    const float* in; u16* outp; int R, C, loc;
    if (t_ < 256)       { in = Wq;  outp = wqkvT;           R = 1024; C = 1024; loc = t_; }
    else if (t_ < 768)  { in = Wkv; outp = wqkvT + 1048576; R = 1024; C = 2048; loc = t_ - 256; }
    else if (t_ < 1024) { in = Wo;  outp = woT;             R = 1024; C = 1024; loc = t_ - 768; }
    else if (t_ < 2048) { in = W1;  outp = w1T;             R = 1024; C = 4096; loc = t_ - 1024; }
    else                { in = W2;  outp = w2T;             R = 4096; C = 1024; loc = t_ - 2048; }
    int tpc = C >> 6;
    int bx = loc % tpc, by = loc / tpc;
    __shared__ float t[64][65];
    int r0 = by * 64, c0 = bx * 64;
    int l16 = tid & 15, grp = tid >> 4;
#pragma unroll
    for (int i = 0; i < 4; ++i) {
        int rr = grp + 16 * i;
        float4 v = *(const float4*)(in + (size_t)(r0 + rr) * C + c0 + l16 * 4);
        t[rr][l16 * 4 + 0] = v.x;
        t[rr][l16 * 4 + 1] = v.y;
        t[rr][l16 * 4 + 2] = v.z;
        t[rr][l16 * 4 + 3] = v.w;
    }
    __syncthreads();
#pragma unroll
    for (int i = 0; i < 4; ++i) {
        int cc = grp + 16 * i;
        ushort4 o;
        o.x = f2bf(t[l16 * 4 + 0][cc]);
        o.y = f2bf(t[l16 * 4 + 1][cc]);
        o.z = f2bf(t[l16 * 4 + 2][cc]);
        o.w = f2bf(t[l16 * 4 + 3][cc]);
        *(ushort4*)(outp + (size_t)(c0 + cc) * R + r0 + l16 * 4) = o;
    }
}

// ---------------- LN + modulate -> bf16 -------------------------------------------
// INLINE_MOD=1: compute shift/scale from modp(8 partials)+bada (L2-resident).
// INLINE_MOD=0: read reduced mod.
template <int INLINE_MOD>
__global__ __launch_bounds__(256) void ln_mod(const float* __restrict__ x,
                                              const float* __restrict__ msrc,
                                              const float* __restrict__ bada,
                                              int shift_c, int scale_c,
                                              u16* __restrict__ h) {
    int row = blockIdx.x;
    int b = row >> 10;
    int tid = threadIdx.x, w = tid >> 6;
    float4 xv = ((const float4*)(x + (size_t)row * D_))[tid];
    float s  = xv.x + xv.y + xv.z + xv.w;
    float s2 = xv.x * xv.x + xv.y * xv.y + xv.z * xv.z + xv.w * xv.w;
#pragma unroll
    for (int m = 1; m <= 32; m <<= 1) { s += __shfl_xor(s, m); s2 += __shfl_xor(s2, m); }
    __shared__ float red[8];
    if ((tid & 63) == 0) { red[w * 2] = s; red[w * 2 + 1] = s2; }
    __syncthreads();
    float S  = red[0] + red[2] + red[4] + red[6];
    float S2 = red[1] + red[3] + red[5] + red[7];
    float mu = S * (1.f / D_);
    float var = S2 * (1.f / D_) - mu * mu;
    float rstd = rsqrtf(var + 1e-6f);
    int d0 = tid * 4;
    float4 shv, scv;
    if (INLINE_MOD) {
        shv = *(const float4*)(bada + shift_c * D_ + d0);
        scv = *(const float4*)(bada + scale_c * D_ + d0);
#pragma unroll
        for (int ks = 0; ks < 8; ++ks) {
            const float* p = msrc + (size_t)(ks * 4 + b) * SIXD;
            float4 p1 = *(const float4*)(p + shift_c * D_ + d0);
            float4 p2 = *(const float4*)(p + scale_c * D_ + d0);
            shv.x += p1.x; shv.y += p1.y; shv.z += p1.z; shv.w += p1.w;
            scv.x += p2.x; scv.y += p2.y; scv.z += p2.z; scv.w += p2.w;
        }
    } else {
        shv = *(const float4*)(msrc + b * SIXD + shift_c * D_ + d0);
        scv = *(const float4*)(msrc + b * SIXD + scale_c * D_ + d0);
    }
    ushort4 o;
    o.x = f2bf((xv.x - mu) * rstd * (1.f + scv.x) + shv.x);
    o.y = f2bf((xv.y - mu) * rstd * (1.f + scv.y) + shv.y);
    o.z = f2bf((xv.z - mu) * rstd * (1.f + scv.z) + shv.z);
    o.w = f2bf((xv.w - mu) * rstd * (1.f + scv.w) + shv.w);
    *(ushort4*)(h + (size_t)row * D_ + d0) = o;
}

// ---------------- qkv GEMM (8 waves, counted 2-phase) + fused mod-reduce tail -----
// blocks 0..767: qkv 128x128 tiles (24 n x 32 m).  blocks 768..815: reduce_mod.
__global__ __launch_bounds__(512) void gemm_qkv(const u16* __restrict__ A,
                                                const u16* __restrict__ Bt,
                                                const float* __restrict__ bias,
                                                const float* __restrict__ bias2,
                                                u16* __restrict__ out,
                                                const float* __restrict__ modp,
                                                const float* __restrict__ bada,
                                                float* __restrict__ mod,
                                                int M, int Nn, int K) {
    if (blockIdx.x >= 768) {
        int idx = (blockIdx.x - 768) * 512 + threadIdx.x;   // 0..24575
        int b = idx / SIXD, col = idx % SIXD;
        float s = bada[col];
#pragma unroll
        for (int ks = 0; ks < 8; ++ks)
            s += modp[(size_t)(ks * 4 + b) * SIXD + col];
        mod[b * SIXD + col] = s;
        return;
    }
    __shared__ char lds[2][32768];
    const int tid = threadIdx.x;
    const int w = tid >> 6, lane = tid & 63;
    const int li = lane & 15, lg = lane >> 4;
    const int flat = blockIdx.x;
    const int wg = (flat & 7) * 96 + (flat >> 3);
    const int m0 = (wg / 24) * 128, n0 = (wg % 24) * 128;
    const int wr = w >> 1, wc = w & 1;     // 4 M-waves x 2 N-waves; per wave 32x64

    f32x4 acc[2][4];
#pragma unroll
    for (int i = 0; i < 2; ++i)
#pragma unroll
        for (int j = 0; j < 4; ++j) acc[i][j] = (f32x4){0.f, 0.f, 0.f, 0.f};

    auto STAGE = [&](int kk, char* buf) {
#pragma unroll
        for (int j = 0; j < 4; ++j) {
            int basec = j * 512 + w * 64;
            int idx = basec + lane;
            int idl = idx & 1023;
            int row = idl >> 3, cc = idl & 7;
            const u16* src;
            if (idx < 1024)
                src = A + (size_t)(m0 + row) * K + kk + ((cc ^ (row & 7)) << 3);
            else
                src = Bt + (size_t)(n0 + row) * K + kk + ((cc ^ (row & 7)) << 3);
            gload16(src, buf + basec * 16);
        }
    };

    const int nt = K >> 6;
    STAGE(0, lds[0]);
    __syncthreads();
    int cur = 0;
    for (int t = 0; t < nt; ++t) {
        if (t + 1 < nt) { STAGE((t + 1) << 6, lds[cur ^ 1]); WAITV(4); }
        else WAITV(0);
        __builtin_amdgcn_s_barrier();
        __builtin_amdgcn_sched_barrier(0);
        const char* Ab = lds[cur];
        const char* Bb = lds[cur] + 16384;
#pragma unroll
        for (int hh = 0; hh < 2; ++hh) {
            s16x8 af[2], bfr[4];
#pragma unroll
            for (int mi = 0; mi < 2; ++mi) {
                int r = wr * 32 + mi * 16 + li;
                af[mi] = *(const s16x8*)(Ab + r * 128 + (((hh * 4 + lg) ^ (r & 7)) << 4));
            }
#pragma unroll
            for (int nj = 0; nj < 4; ++nj) {
                int r = wc * 64 + nj * 16 + li;
                bfr[nj] = *(const s16x8*)(Bb + r * 128 + (((hh * 4 + lg) ^ (r & 7)) << 4));
            }
#pragma unroll
            for (int mi = 0; mi < 2; ++mi)
#pragma unroll
                for (int nj = 0; nj < 4; ++nj)
                    acc[mi][nj] = __builtin_amdgcn_mfma_f32_16x16x32_bf16(
                        af[mi], bfr[nj], acc[mi][nj], 0, 0, 0);
        }
        __builtin_amdgcn_s_barrier();
        cur ^= 1;
    }

#pragma unroll
    for (int mi = 0; mi < 2; ++mi) {
#pragma unroll
        for (int nj = 0; nj < 4; ++nj) {
            int col = n0 + wc * 64 + nj * 16 + li;
            float bv = (col < D_) ? bias[col] : bias2[col - D_];
#pragma unroll
            for (int rg = 0; rg < 4; ++rg) {
                int grow = m0 + wr * 32 + mi * 16 + 4 * lg + rg;
                float v = acc[mi][nj][rg] + bv;
                int b = grow >> 10, n = grow & 1023;
                if (col < D_) {
                    int hd = col >> 6, dh = col & 63;
                    out[(((size_t)(b * H_ + hd)) * N_ + n) * DH_ + dh] = f2bf(v);
                } else if (col < 2 * D_) {
                    int c2 = col - D_;
                    int hd = c2 >> 6, dh = c2 & 63;
                    out[4194304u + (((size_t)(b * H_ + hd)) * N_ + n) * DH_ + dh] = f2bf(v);
                } else {
                    int c2 = col - 2 * D_;
                    int hd = c2 >> 6, dh = c2 & 63;
                    out[8388608u + (((size_t)(b * H_ + hd)) * DH_ + dh) * N_ + n] = f2bf(v);
                }
            }
        }
    }
}

// ---------------- 128x128, 8 waves (512 thr), counted-vmcnt (o-proj, W2) ----------
template <int EPI>
__global__ __launch_bounds__(512) void gemm_bt(const u16* __restrict__ A,
                                               const u16* __restrict__ Bt,
                                               const float* __restrict__ bias,
                                               void* __restrict__ out,
                                               const float* __restrict__ xres,
                                               const float* __restrict__ mod,
                                               int M, int Nn, int K, int gate_c) {
    __shared__ char lds[2][32768];
    const int tid = threadIdx.x;
    const int w = tid >> 6, lane = tid & 63;
    const int li = lane & 15, lg = lane >> 4;
    const int nwg = gridDim.x * gridDim.y;
    const int flat = blockIdx.y * gridDim.x + blockIdx.x;
    const int wg = (flat & 7) * (nwg >> 3) + (flat >> 3);
    const int m0 = (wg / gridDim.x) * 128, n0 = (wg % gridDim.x) * 128;
    const int wr = w >> 1, wc = w & 1;

    f32x4 acc[2][4];
#pragma unroll
    for (int i = 0; i < 2; ++i)
#pragma unroll
        for (int j = 0; j < 4; ++j) acc[i][j] = (f32x4){0.f, 0.f, 0.f, 0.f};

    auto STAGE = [&](int kk, char* buf) {
#pragma unroll
        for (int j = 0; j < 4; ++j) {
            int basec = j * 512 + w * 64;
            int idx = basec + lane;
            int idl = idx & 1023;
            int row = idl >> 3, cc = idl & 7;
            const u16* src;
            if (idx < 1024)
                src = A + (size_t)(m0 + row) * K + kk + ((cc ^ (row & 7)) << 3);
            else
                src = Bt + (size_t)(n0 + row) * K + kk + ((cc ^ (row & 7)) << 3);
            gload16(src, buf + basec * 16);
        }
    };

    const int nt = K >> 6;
    STAGE(0, lds[0]);
    __syncthreads();
    int cur = 0;
    for (int t = 0; t < nt; ++t) {
        if (t + 1 < nt) { STAGE((t + 1) << 6, lds[cur ^ 1]); WAITV(4); }
        else WAITV(0);
        __builtin_amdgcn_s_barrier();
        __builtin_amdgcn_sched_barrier(0);
        const char* Ab = lds[cur];
        const char* Bb = lds[cur] + 16384;
#pragma unroll
        for (int hh = 0; hh < 2; ++hh) {
            s16x8 af[2], bfr[4];
#pragma unroll
            for (int mi = 0; mi < 2; ++mi) {
                int r = wr * 32 + mi * 16 + li;
                af[mi] = *(const s16x8*)(Ab + r * 128 + (((hh * 4 + lg) ^ (r & 7)) << 4));
            }
#pragma unroll
            for (int nj = 0; nj < 4; ++nj) {
                int r = wc * 64 + nj * 16 + li;
                bfr[nj] = *(const s16x8*)(Bb + r * 128 + (((hh * 4 + lg) ^ (r & 7)) << 4));
            }
#pragma unroll
            for (int mi = 0; mi < 2; ++mi)
#pragma unroll
                for (int nj = 0; nj < 4; ++nj)
                    acc[mi][nj] = __builtin_amdgcn_mfma_f32_16x16x32_bf16(
                        af[mi], bfr[nj], acc[mi][nj], 0, 0, 0);
        }
        __builtin_amdgcn_s_barrier();
        cur ^= 1;
    }

#pragma unroll
    for (int mi = 0; mi < 2; ++mi) {
#pragma unroll
        for (int nj = 0; nj < 4; ++nj) {
            int col = n0 + wc * 64 + nj * 16 + li;
            float bv = bias[col];
#pragma unroll
            for (int rg = 0; rg < 4; ++rg) {
                int grow = m0 + wr * 32 + mi * 16 + 4 * lg + rg;
                float v = acc[mi][nj][rg] + bv;
                int b = grow >> 10;
                size_t off = (size_t)grow * D_ + col;
                float g = mod[b * SIXD + gate_c * D_ + col];
                ((float*)out)[off] = xres[off] + g * v;
            }
        }
    }
}

// ---------------- 256x256 tile GEMM (8 waves), dbuf + plain syncthreads, gelu -----
__global__ __launch_bounds__(512, 2) void gemm256_gelu(const u16* __restrict__ A,
                                                       const u16* __restrict__ Bt,
                                                       const float* __restrict__ bias,
                                                       u16* __restrict__ out,
                                                       int M, int Nn, int K) {
    __shared__ char lds[2][65536];
    const int tid = threadIdx.x;
    const int w = tid >> 6, lane = tid & 63;
    const int li = lane & 15, lg = lane >> 4;
    const int wr = w >> 1, wc = w & 1;

    const int flat = blockIdx.x;
    const int wg = (flat & 7) * 32 + (flat >> 3);
    const int mg = wg >> 6, r_ = wg & 63;
    const int mt = mg * 4 + (r_ & 3), nt_ = r_ >> 2;
    const int m0 = mt * 256, n0 = nt_ * 256;

    f32x4 acc[4][8];
#pragma unroll
    for (int i = 0; i < 4; ++i)
#pragma unroll
        for (int j = 0; j < 8; ++j) acc[i][j] = (f32x4){0.f, 0.f, 0.f, 0.f};

    auto STAGE = [&](int kk, char* buf) {
#pragma unroll
        for (int j = 0; j < 4; ++j) {
            int basec = j * 512 + w * 64;
            int idx = basec + lane;
            int row = idx >> 3, cc = idx & 7;
            gload16(A + (size_t)(m0 + row) * K + kk + ((cc ^ (row & 7)) << 3),
                    buf + basec * 16);
            gload16(Bt + (size_t)(n0 + row) * K + kk + ((cc ^ (row & 7)) << 3),
                    buf + 32768 + basec * 16);
        }
    };

    const int nt = K >> 6;
    STAGE(0, lds[0]);
    __syncthreads();
    int cur = 0;
    for (int t = 0; t < nt; ++t) {
        if (t + 1 < nt) STAGE((t + 1) << 6, lds[cur ^ 1]);
        const char* Ab = lds[cur];
        const char* Bb = lds[cur] + 32768;
#pragma unroll
        for (int hh = 0; hh < 2; ++hh) {
            s16x8 af[4], bfr[8];
#pragma unroll
            for (int mi = 0; mi < 4; ++mi) {
                int r = wr * 64 + mi * 16 + li;
                af[mi] = *(const s16x8*)(Ab + r * 128 + (((hh * 4 + lg) ^ (r & 7)) << 4));
            }
#pragma unroll
            for (int nj = 0; nj < 8; ++nj) {
                int r = wc * 128 + nj * 16 + li;
                bfr[nj] = *(const s16x8*)(Bb + r * 128 + (((hh * 4 + lg) ^ (r & 7)) << 4));
            }
#pragma unroll
            for (int mi = 0; mi < 4; ++mi)
#pragma unroll
                for (int nj = 0; nj < 8; ++nj)
                    acc[mi][nj] = __builtin_amdgcn_mfma_f32_16x16x32_bf16(
                        af[mi], bfr[nj], acc[mi][nj], 0, 0, 0);
        }
        __syncthreads();
        cur ^= 1;
    }

#pragma unroll
    for (int nj = 0; nj < 8; ++nj) {
        int col = n0 + wc * 128 + nj * 16 + li;
        float bv = bias[col];
#pragma unroll
        for (int mi = 0; mi < 4; ++mi) {
#pragma unroll
            for (int rg = 0; rg < 4; ++rg) {
                int grow = m0 + wr * 64 + mi * 16 + 4 * lg + rg;
                float v = acc[mi][nj][rg] + bv;
                float u = 0.7978845608028654f * v * (1.f + 0.044715f * v * v);
                u = fminf(fmaxf(u, -15.f), 15.f);
                float e = __expf(2.f * u);
                float th = (e - 1.f) / (e + 1.f);
                out[(size_t)grow * (size_t)Nn + col] = f2bf(0.5f * v * (1.f + th));
            }
        }
    }
}

// ---------------- flash attention: 4 warps x 32 q-rows, 32x32 MFMA, swapped -------
__global__ __launch_bounds__(256) void attn2(const u16* __restrict__ q,
                                             const u16* __restrict__ k,
                                             const u16* __restrict__ vt,
                                             u16* __restrict__ o) {
    __shared__ __align__(16) char qs[16384];
    __shared__ __align__(16) char kv[2][16384];
    const int tid = threadIdx.x, w = tid >> 6, lane = tid & 63;
    const int l31 = lane & 31, hi = lane >> 5;
    const int flat = blockIdx.x;
    const int wgs = (flat & 7) * 64 + (flat >> 3);
    const int bh = wgs >> 3, qt = wgs & 7;
    const size_t base = (size_t)bh * (N_ * DH_);
    const int q0 = qt * 128;

#pragma unroll
    for (int j = 0; j < 4; ++j) {
        int basec = j * 256 + w * 64;
        int idx = basec + lane;
        int row = idx >> 3, cc = idx & 7;
        gload16(q + base + (size_t)(q0 + row) * DH_ + ((cc ^ (row & 7)) << 3),
                qs + basec * 16);
    }
    auto STAGEKV = [&](int t, char* buf) {
#pragma unroll
        for (int j = 0; j < 4; ++j) {
            int basec = j * 256 + w * 64;
            int idx = basec + lane;
            if (idx < 512) {
                int row = idx >> 3, cc = idx & 7;
                gload16(k + base + (size_t)(t * 64 + row) * DH_ + ((cc ^ (row & 7)) << 3),
                        buf + basec * 16);
            } else {
                int i2 = idx - 512;
                int row = i2 >> 3, cc = i2 & 7;
                gload16(vt + base + (size_t)row * N_ + t * 64 + ((cc ^ (row & 7)) << 3),
                        buf + basec * 16);
            }
        }
    };
    STAGEKV(0, kv[0]);
    __syncthreads();

    s16x8 qf[4];
    const int qr = w * 32 + l31;
#pragma unroll
    for (int st = 0; st < 4; ++st)
        qf[st] = *(const s16x8*)(qs + qr * 128 + (((st * 2 + hi) ^ (qr & 7)) << 4));

    f32x16 oa[2];
#pragma unroll
    for (int r = 0; r < 16; ++r) { oa[0][r] = 0.f; oa[1][r] = 0.f; }
    float mrow = -3e38f, lrow = 0.f;
    const float CSC = 0.125f * 1.44269504088896f;

    int cur = 0;
    for (int t = 0; t < 16; ++t) {
        if (t + 1 < 16) STAGEKV(t + 1, kv[cur ^ 1]);
        const char* Kb = kv[cur];
        const char* Vb = kv[cur] + 8192;

        f32x16 s[2];
#pragma unroll
        for (int r = 0; r < 16; ++r) { s[0][r] = 0.f; s[1][r] = 0.f; }
        __builtin_amdgcn_s_setprio(1);
#pragma unroll
        for (int st = 0; st < 4; ++st) {
#pragma unroll
            for (int ks = 0; ks < 2; ++ks) {
                int r = ks * 32 + l31;
                s16x8 ka = *(const s16x8*)(Kb + r * 128 + (((st * 2 + hi) ^ (r & 7)) << 4));
                s[ks] = __builtin_amdgcn_mfma_f32_32x32x16_bf16(ka, qf[st], s[ks], 0, 0, 0);
            }
        }
        __builtin_amdgcn_s_setprio(0);

        float tmax = s[0][0];
#pragma unroll
        for (int r = 1; r < 16; ++r) tmax = fmaxf(tmax, s[0][r]);
#pragma unroll
        for (int r = 0; r < 16; ++r) tmax = fmaxf(tmax, s[1][r]);
        tmax = fmaxf(tmax, __shfl_xor(tmax, 32));
        float mn = fmaxf(mrow, tmax);
        float al = __builtin_amdgcn_exp2f((mrow - mn) * CSC);
        float nmc = -mn * CSC;
        float rs0 = 0.f, rs1 = 0.f;
#pragma unroll
        for (int r = 0; r < 16; ++r) {
            float p0 = __builtin_amdgcn_exp2f(fmaf(s[0][r], CSC, nmc));
            float p1 = __builtin_amdgcn_exp2f(fmaf(s[1][r], CSC, nmc));
            s[0][r] = p0; s[1][r] = p1;
            rs0 += p0; rs1 += p1;
        }
        float rs = rs0 + rs1;
        rs += __shfl_xor(rs, 32);
        lrow = lrow * al + rs;
        mrow = mn;
#pragma unroll
        for (int r = 0; r < 16; ++r) { oa[0][r] *= al; oa[1][r] *= al; }

        unsigned u[16];
#pragma unroll
        for (int ks = 0; ks < 2; ++ks)
#pragma unroll
            for (int j = 0; j < 4; ++j) {
                u[ks * 8 + 2 * j]     = cvtpk(s[ks][4 * j + 0], s[ks][4 * j + 1]);
                u[ks * 8 + 2 * j + 1] = cvtpk(s[ks][4 * j + 2], s[ks][4 * j + 3]);
            }

#pragma unroll
        for (int kstep = 0; kstep < 4; ++kstep) {
            unsigned b0 = u[kstep * 4 + 0], b1 = u[kstep * 4 + 1];
            unsigned b2 = u[kstep * 4 + 2], b3 = u[kstep * 4 + 3];
            asm volatile("v_permlane32_swap_b32 %0, %1" : "+v"(b0), "+v"(b2));
            asm volatile("v_permlane32_swap_b32 %0, %1" : "+v"(b1), "+v"(b3));
            u32x4 pbu = (u32x4){b0, b1, b2, b3};
            s16x8 pb = __builtin_bit_cast(s16x8, pbu);
            __builtin_amdgcn_s_setprio(1);
#pragma unroll
            for (int ds = 0; ds < 2; ++ds) {
                int r = ds * 32 + l31;
                s16x8 va = *(const s16x8*)(Vb + r * 128 + (((kstep * 2 + hi) ^ (r & 7)) << 4));
                oa[ds] = __builtin_amdgcn_mfma_f32_32x32x16_bf16(va, pb, oa[ds], 0, 0, 0);
            }
            __builtin_amdgcn_s_setprio(0);
        }
        __syncthreads();
        cur ^= 1;
    }

    float inv = 1.f / lrow;
#pragma unroll
    for (int ds = 0; ds < 2; ++ds)
#pragma unroll
        for (int j = 0; j < 4; ++j)
#pragma unroll
            for (int t2 = 0; t2 < 2; ++t2) {
                unsigned pk = cvtpk(oa[ds][4 * j + 2 * t2] * inv,
                                    oa[ds][4 * j + 2 * t2 + 1] * inv);
                int row = qr;
                int dch = 4 * ds + j;
                *(unsigned*)(qs + row * 128 + ((dch ^ (row & 7)) << 4) +
                             (4 * hi + 2 * t2) * 2) = pk;
            }
    __syncthreads();
    {
        int r = tid >> 1, h2 = tid & 1;
        const int b = bh >> 4, hd = bh & 15;
        size_t obase = ((size_t)(b * N_ + q0 + r)) * D_ + hd * DH_;
#pragma unroll
        for (int c = 0; c < 4; ++c) {
            int c2 = h2 * 4 + c;
            s16x8 v = *(const s16x8*)(qs + r * 128 + ((c2 ^ (r & 7)) << 4));
            *(s16x8*)(o + obase + c2 * 8) = v;
        }
    }
}

// ---------------------------------------------------------------------------------
extern "C" void kernel_launch(void* const* d_in, const int* in_sizes, int n_in,
                              void* d_out, int out_size, void* d_ws, size_t ws_size,
                              hipStream_t stream) {
    const float* x    = (const float*)d_in[0];
    const float* c    = (const float*)d_in[1];
    const float* Wq   = (const float*)d_in[2];
    const float* bq   = (const float*)d_in[3];
    const float* Wkv  = (const float*)d_in[4];
    const float* bkv  = (const float*)d_in[5];
    const float* Wo   = (const float*)d_in[6];
    const float* bo   = (const float*)d_in[7];
    const float* W1   = (const float*)d_in[8];
    const float* b1   = (const float*)d_in[9];
    const float* W2   = (const float*)d_in[10];
    const float* b2   = (const float*)d_in[11];
    const float* Wada = (const float*)d_in[12];
    const float* bada = (const float*)d_in[13];

    char* ws = (char*)d_ws;
    const size_t MB = 1024 * 1024;
    u16*   wqkvT = (u16*)(ws + 0);       // 6MB
    u16*   woT  = (u16*)(ws + 6 * MB);   // 2MB
    u16*   w1T  = (u16*)(ws + 8 * MB);   // 8MB
    u16*   w2T  = (u16*)(ws + 16 * MB);  // 8MB
    float* mod  = (float*)(ws + 24 * MB);            // 96KB
    float* modp = (float*)(ws + 24 * MB + 131072);   // 768KB partials
    u16*   h    = (u16*)(ws + 25 * MB);  // 8MB
    u16*   qb   = (u16*)(ws + 33 * MB);  // 24MB: q | k(+4M elems) | vt(+8M elems)
    u16*   ao   = (u16*)(ws + 57 * MB);  // 8MB
    float* x1   = (float*)(ws + 65 * MB);// 16MB
    u16*   m1   = (u16*)(ws + 33 * MB);  // 32MB, reuses qkv+ao (dead by then)
    float* outp = (float*)d_out;

    prep_all<<<3840, 256, 0, stream>>>(Wq, Wkv, Wo, W1, W2, c, Wada,
                                       wqkvT, woT, w1T, w2T, modp);

    // LN1 computes its own shift/scale from modp (no reduce_mod dependency)
    ln_mod<1><<<M_, 256, 0, stream>>>(x, modp, bada, 0, 1, h);

    // qkv (768 blocks) + fused mod reduce (48 tail blocks)
    gemm_qkv<<<816, 512, 0, stream>>>(h, wqkvT, bq, bkv, qb, modp, bada, mod,
                                      M_, 3 * D_, D_);

    attn2<<<512, 256, 0, stream>>>(qb, qb + 4194304, qb + 8388608, ao);

    gemm_bt<2><<<dim3(8, 32), 512, 0, stream>>>(ao, woT, bo, x1, x, mod, M_, D_, D_, 2);

    ln_mod<0><<<M_, 256, 0, stream>>>(x1, mod, bada, 3, 4, h);

    gemm256_gelu<<<256, 512, 0, stream>>>(h, w1T, b1, m1, M_, 4 * D_, D_);
    gemm_bt<4><<<dim3(8, 32), 512, 0, stream>>>(m1, w2T, b2, outp, x1, mod, M_, D_, 4 * D_, 5);
}

// Round 15
// 216.984 us; speedup vs baseline: 1.0337x; 1.0337x over previous
//
#include <hip/hip_runtime.h>
#include <hip/hip_bf16.h>
#include <cstdint>

typedef __attribute__((ext_vector_type(4))) float f32x4;
typedef __attribute__((ext_vector_type(16))) float f32x16;
typedef __attribute__((ext_vector_type(8))) short s16x8;
typedef __attribute__((ext_vector_type(4))) unsigned u32x4;
typedef unsigned short u16;

#define B_  4
#define N_  1024
#define D_  1024
#define H_  16
#define DH_ 64
#define M_  4096      // B_*N_
#define SIXD 6144

#define WAITV(n) asm volatile("s_waitcnt vmcnt(" #n ")" ::: "memory")

__device__ __forceinline__ u16 f2bf(float f) {
    unsigned u = __builtin_bit_cast(unsigned, f);
    unsigned r = (u + 0x7fffu + ((u >> 16) & 1u)) >> 16;
    return (u16)r;
}

__device__ __forceinline__ unsigned cvtpk(float a, float b) {
    unsigned r;
    asm("v_cvt_pk_bf16_f32 %0, %1, %2" : "=v"(r) : "v"(a), "v"(b));
    return r;
}

__device__ __forceinline__ void gload16(const void* g, void* l) {
    __builtin_amdgcn_global_load_lds((const __attribute__((address_space(1))) void*)g,
                                     (__attribute__((address_space(3))) void*)l,
                                     16, 0, 0);
}

// ------- fused prep: modk K-split partials (first, latency) + 64x64 transposes ----
__global__ __launch_bounds__(256) void prep_all(const float* __restrict__ Wq,
                                                const float* __restrict__ Wkv,
                                                const float* __restrict__ Wo,
                                                const float* __restrict__ W1,
                                                const float* __restrict__ W2,
                                                const float* __restrict__ c,
                                                const float* __restrict__ Wada,
                                                u16* __restrict__ wqkvT,
                                                u16* __restrict__ woT,
                                                u16* __restrict__ w1T,
                                                u16* __restrict__ w2T,
                                                float* __restrict__ modp) {
    int id = blockIdx.x;
    int tid = threadIdx.x;
    if (id < 768) {
        __shared__ float sc[128];
        int colblk = id % 24, b = (id / 24) & 3, ks = id / 96;
        int col = colblk * 256 + tid;
        int k0 = ks * 128;
        if (tid < 128) {
            float v = c[b * D_ + k0 + tid];
            sc[tid] = v / (1.f + __expf(-v));
        }
        __syncthreads();
        float a0 = 0.f, a1 = 0.f, a2 = 0.f, a3 = 0.f;
#pragma unroll 4
        for (int k = 0; k < 128; k += 4) {
            a0 = fmaf(sc[k + 0], Wada[(size_t)(k0 + k + 0) * SIXD + col], a0);
            a1 = fmaf(sc[k + 1], Wada[(size_t)(k0 + k + 1) * SIXD + col], a1);
            a2 = fmaf(sc[k + 2], Wada[(size_t)(k0 + k + 2) * SIXD + col], a2);
            a3 = fmaf(sc[k + 3], Wada[(size_t)(k0 + k + 3) * SIXD + col], a3);
        }
        modp[(size_t)(ks * 4 + b) * SIXD + col] = (a0 + a1) + (a2 + a3);
        return;
    }
    int t_ = id - 768;
    const float* in; u16* outp; int R, C, loc;
    if (t_ < 256)       { in = Wq;  outp = wqkvT;           R = 1024; C = 1024; loc = t_; }
    else if (t_ < 768)  { in = Wkv; outp = wqkvT + 1048576; R = 1024; C = 2048; loc = t_ - 256; }
    else if (t_ < 1024) { in = Wo;  outp = woT;             R = 1024; C = 1024; loc = t_ - 768; }
    else if (t_ < 2048) { in = W1;  outp = w1T;             R = 1024; C = 4096; loc = t_ - 1024; }
    else                { in = W2;  outp = w2T;             R = 4096; C = 1024; loc = t_ - 2048; }
    int tpc = C >> 6;
    int bx = loc % tpc, by = loc / tpc;
    __shared__ float t[64][65];
    int r0 = by * 64, c0 = bx * 64;
    int l16 = tid & 15, grp = tid >> 4;
#pragma unroll
    for (int i = 0; i < 4; ++i) {
        int rr = grp + 16 * i;
        float4 v = *(const float4*)(in + (size_t)(r0 + rr) * C + c0 + l16 * 4);
        t[rr][l16 * 4 + 0] = v.x;
        t[rr][l16 * 4 + 1] = v.y;
        t[rr][l16 * 4 + 2] = v.z;
        t[rr][l16 * 4 + 3] = v.w;
    }
    __syncthreads();
#pragma unroll
    for (int i = 0; i < 4; ++i) {
        int cc = grp + 16 * i;
        ushort4 o;
        o.x = f2bf(t[l16 * 4 + 0][cc]);
        o.y = f2bf(t[l16 * 4 + 1][cc]);
        o.z = f2bf(t[l16 * 4 + 2][cc]);
        o.w = f2bf(t[l16 * 4 + 3][cc]);
        *(ushort4*)(outp + (size_t)(c0 + cc) * R + r0 + l16 * 4) = o;
    }
}

// ---------------- reduce modk partials: mod = sum_ks modp + bada ------------------
__global__ __launch_bounds__(256) void reduce_mod(const float* __restrict__ modp,
                                                  const float* __restrict__ bada,
                                                  float* __restrict__ mod) {
    int col = blockIdx.x * 256 + threadIdx.x;
    int b = blockIdx.y;
    float s = bada[col];
#pragma unroll
    for (int ks = 0; ks < 8; ++ks)
        s += modp[(size_t)(ks * 4 + b) * SIXD + col];
    mod[b * SIXD + col] = s;
}

// ---------------- LN + modulate -> bf16 -------------------------------------------
__global__ __launch_bounds__(256) void ln_mod(const float* __restrict__ x,
                                              const float* __restrict__ mod,
                                              int shift_c, int scale_c,
                                              u16* __restrict__ h) {
    int row = blockIdx.x;
    int b = row >> 10;
    int tid = threadIdx.x, w = tid >> 6;
    float4 xv = ((const float4*)(x + (size_t)row * D_))[tid];
    float s  = xv.x + xv.y + xv.z + xv.w;
    float s2 = xv.x * xv.x + xv.y * xv.y + xv.z * xv.z + xv.w * xv.w;
#pragma unroll
    for (int m = 1; m <= 32; m <<= 1) { s += __shfl_xor(s, m); s2 += __shfl_xor(s2, m); }
    __shared__ float red[8];
    if ((tid & 63) == 0) { red[w * 2] = s; red[w * 2 + 1] = s2; }
    __syncthreads();
    float S  = red[0] + red[2] + red[4] + red[6];
    float S2 = red[1] + red[3] + red[5] + red[7];
    float mu = S * (1.f / D_);
    float var = S2 * (1.f / D_) - mu * mu;
    float rstd = rsqrtf(var + 1e-6f);
    int d0 = tid * 4;
    float4 shv = *(const float4*)(mod + b * SIXD + shift_c * D_ + d0);
    float4 scv = *(const float4*)(mod + b * SIXD + scale_c * D_ + d0);
    ushort4 o;
    o.x = f2bf((xv.x - mu) * rstd * (1.f + scv.x) + shv.x);
    o.y = f2bf((xv.y - mu) * rstd * (1.f + scv.y) + shv.y);
    o.z = f2bf((xv.z - mu) * rstd * (1.f + scv.z) + shv.z);
    o.w = f2bf((xv.w - mu) * rstd * (1.f + scv.w) + shv.w);
    *(ushort4*)(h + (size_t)row * D_ + d0) = o;
}

// ---------------- qkv GEMM: 128x128, 8 waves (512 thr), counted-vmcnt 2-phase -----
__global__ __launch_bounds__(512) void gemm_qkv(const u16* __restrict__ A,
                                                const u16* __restrict__ Bt,
                                                const float* __restrict__ bias,
                                                const float* __restrict__ bias2,
                                                u16* __restrict__ out,
                                                int M, int Nn, int K) {
    __shared__ char lds[2][32768];
    const int tid = threadIdx.x;
    const int w = tid >> 6, lane = tid & 63;
    const int li = lane & 15, lg = lane >> 4;
    const int nwg = gridDim.x * gridDim.y;
    const int flat = blockIdx.y * gridDim.x + blockIdx.x;
    const int wg = (flat & 7) * (nwg >> 3) + (flat >> 3);
    const int m0 = (wg / gridDim.x) * 128, n0 = (wg % gridDim.x) * 128;
    const int wr = w >> 1, wc = w & 1;     // 4 M-waves x 2 N-waves; per wave 32x64

    f32x4 acc[2][4];
#pragma unroll
    for (int i = 0; i < 2; ++i)
#pragma unroll
        for (int j = 0; j < 4; ++j) acc[i][j] = (f32x4){0.f, 0.f, 0.f, 0.f};

    auto STAGE = [&](int kk, char* buf) {
#pragma unroll
        for (int j = 0; j < 4; ++j) {
            int basec = j * 512 + w * 64;
            int idx = basec + lane;
            int idl = idx & 1023;
            int row = idl >> 3, cc = idl & 7;
            const u16* src;
            if (idx < 1024)
                src = A + (size_t)(m0 + row) * K + kk + ((cc ^ (row & 7)) << 3);
            else
                src = Bt + (size_t)(n0 + row) * K + kk + ((cc ^ (row & 7)) << 3);
            gload16(src, buf + basec * 16);
        }
    };

    const int nt = K >> 6;
    STAGE(0, lds[0]);
    __syncthreads();
    int cur = 0;
    for (int t = 0; t < nt; ++t) {
        if (t + 1 < nt) { STAGE((t + 1) << 6, lds[cur ^ 1]); WAITV(4); }
        else WAITV(0);
        __builtin_amdgcn_s_barrier();
        __builtin_amdgcn_sched_barrier(0);
        const char* Ab = lds[cur];
        const char* Bb = lds[cur] + 16384;
#pragma unroll
        for (int hh = 0; hh < 2; ++hh) {
            s16x8 af[2], bfr[4];
#pragma unroll
            for (int mi = 0; mi < 2; ++mi) {
                int r = wr * 32 + mi * 16 + li;
                af[mi] = *(const s16x8*)(Ab + r * 128 + (((hh * 4 + lg) ^ (r & 7)) << 4));
            }
#pragma unroll
            for (int nj = 0; nj < 4; ++nj) {
                int r = wc * 64 + nj * 16 + li;
                bfr[nj] = *(const s16x8*)(Bb + r * 128 + (((hh * 4 + lg) ^ (r & 7)) << 4));
            }
#pragma unroll
            for (int mi = 0; mi < 2; ++mi)
#pragma unroll
                for (int nj = 0; nj < 4; ++nj)
                    acc[mi][nj] = __builtin_amdgcn_mfma_f32_16x16x32_bf16(
                        af[mi], bfr[nj], acc[mi][nj], 0, 0, 0);
        }
        __builtin_amdgcn_s_barrier();
        cur ^= 1;
    }

#pragma unroll
    for (int mi = 0; mi < 2; ++mi) {
#pragma unroll
        for (int nj = 0; nj < 4; ++nj) {
            int col = n0 + wc * 64 + nj * 16 + li;
            float bv = (col < D_) ? bias[col] : bias2[col - D_];
#pragma unroll
            for (int rg = 0; rg < 4; ++rg) {
                int grow = m0 + wr * 32 + mi * 16 + 4 * lg + rg;
                float v = acc[mi][nj][rg] + bv;
                int b = grow >> 10, n = grow & 1023;
                if (col < D_) {
                    int hd = col >> 6, dh = col & 63;
                    out[(((size_t)(b * H_ + hd)) * N_ + n) * DH_ + dh] = f2bf(v);
                } else if (col < 2 * D_) {
                    int c2 = col - D_;
                    int hd = c2 >> 6, dh = c2 & 63;
                    out[4194304u + (((size_t)(b * H_ + hd)) * N_ + n) * DH_ + dh] = f2bf(v);
                } else {
                    int c2 = col - 2 * D_;
                    int hd = c2 >> 6, dh = c2 & 63;
                    out[8388608u + (((size_t)(b * H_ + hd)) * DH_ + dh) * N_ + n] = f2bf(v);
                }
            }
        }
    }
}

// ---------------- 128x128, 8 waves (512 thr), counted-vmcnt (o-proj, W2) ----------
// EPI 2/4: out = xres + mod[gate]*val  (f32 out)
template <int EPI>
__global__ __launch_bounds__(512) void gemm_bt(const u16* __restrict__ A,
                                               const u16* __restrict__ Bt,
                                               const float* __restrict__ bias,
                                               void* __restrict__ out,
                                               const float* __restrict__ xres,
                                               const float* __restrict__ mod,
                                               int M, int Nn, int K, int gate_c) {
    __shared__ char lds[2][32768];
    const int tid = threadIdx.x;
    const int w = tid >> 6, lane = tid & 63;
    const int li = lane & 15, lg = lane >> 4;
    const int nwg = gridDim.x * gridDim.y;
    const int flat = blockIdx.y * gridDim.x + blockIdx.x;
    const int wg = (flat & 7) * (nwg >> 3) + (flat >> 3);
    const int m0 = (wg / gridDim.x) * 128, n0 = (wg % gridDim.x) * 128;
    const int wr = w >> 1, wc = w & 1;     // 4 M-waves x 2 N-waves

    f32x4 acc[2][4];
#pragma unroll
    for (int i = 0; i < 2; ++i)
#pragma unroll
        for (int j = 0; j < 4; ++j) acc[i][j] = (f32x4){0.f, 0.f, 0.f, 0.f};

    auto STAGE = [&](int kk, char* buf) {
#pragma unroll
        for (int j = 0; j < 4; ++j) {
            int basec = j * 512 + w * 64;
            int idx = basec + lane;
            int idl = idx & 1023;
            int row = idl >> 3, cc = idl & 7;
            const u16* src;
            if (idx < 1024)
                src = A + (size_t)(m0 + row) * K + kk + ((cc ^ (row & 7)) << 3);
            else
                src = Bt + (size_t)(n0 + row) * K + kk + ((cc ^ (row & 7)) << 3);
            gload16(src, buf + basec * 16);
        }
    };

    const int nt = K >> 6;
    STAGE(0, lds[0]);
    __syncthreads();
    int cur = 0;
    for (int t = 0; t < nt; ++t) {
        if (t + 1 < nt) { STAGE((t + 1) << 6, lds[cur ^ 1]); WAITV(4); }
        else WAITV(0);
        __builtin_amdgcn_s_barrier();
        __builtin_amdgcn_sched_barrier(0);
        const char* Ab = lds[cur];
        const char* Bb = lds[cur] + 16384;
#pragma unroll
        for (int hh = 0; hh < 2; ++hh) {
            s16x8 af[2], bfr[4];
#pragma unroll
            for (int mi = 0; mi < 2; ++mi) {
                int r = wr * 32 + mi * 16 + li;
                af[mi] = *(const s16x8*)(Ab + r * 128 + (((hh * 4 + lg) ^ (r & 7)) << 4));
            }
#pragma unroll
            for (int nj = 0; nj < 4; ++nj) {
                int r = wc * 64 + nj * 16 + li;
                bfr[nj] = *(const s16x8*)(Bb + r * 128 + (((hh * 4 + lg) ^ (r & 7)) << 4));
            }
#pragma unroll
            for (int mi = 0; mi < 2; ++mi)
#pragma unroll
                for (int nj = 0; nj < 4; ++nj)
                    acc[mi][nj] = __builtin_amdgcn_mfma_f32_16x16x32_bf16(
                        af[mi], bfr[nj], acc[mi][nj], 0, 0, 0);
        }
        __builtin_amdgcn_s_barrier();
        cur ^= 1;
    }

#pragma unroll
    for (int mi = 0; mi < 2; ++mi) {
#pragma unroll
        for (int nj = 0; nj < 4; ++nj) {
            int col = n0 + wc * 64 + nj * 16 + li;
            float bv = bias[col];
#pragma unroll
            for (int rg = 0; rg < 4; ++rg) {
                int grow = m0 + wr * 32 + mi * 16 + 4 * lg + rg;
                float v = acc[mi][nj][rg] + bv;
                int b = grow >> 10;
                size_t off = (size_t)grow * D_ + col;
                float g = mod[b * SIXD + gate_c * D_ + col];
                ((float*)out)[off] = xres[off] + g * v;
            }
        }
    }
}

// ---------------- 256x256 tile GEMM (8 waves), dbuf + plain syncthreads, gelu -----
__global__ __launch_bounds__(512, 2) void gemm256_gelu(const u16* __restrict__ A,
                                                       const u16* __restrict__ Bt,
                                                       const float* __restrict__ bias,
                                                       u16* __restrict__ out,
                                                       int M, int Nn, int K) {
    __shared__ char lds[2][65536];
    const int tid = threadIdx.x;
    const int w = tid >> 6, lane = tid & 63;
    const int li = lane & 15, lg = lane >> 4;
    const int wr = w >> 1, wc = w & 1;

    const int flat = blockIdx.x;
    const int wg = (flat & 7) * 32 + (flat >> 3);
    const int mg = wg >> 6, r_ = wg & 63;
    const int mt = mg * 4 + (r_ & 3), nt_ = r_ >> 2;
    const int m0 = mt * 256, n0 = nt_ * 256;

    f32x4 acc[4][8];
#pragma unroll
    for (int i = 0; i < 4; ++i)
#pragma unroll
        for (int j = 0; j < 8; ++j) acc[i][j] = (f32x4){0.f, 0.f, 0.f, 0.f};

    auto STAGE = [&](int kk, char* buf) {
#pragma unroll
        for (int j = 0; j < 4; ++j) {
            int basec = j * 512 + w * 64;
            int idx = basec + lane;
            int row = idx >> 3, cc = idx & 7;
            gload16(A + (size_t)(m0 + row) * K + kk + ((cc ^ (row & 7)) << 3),
                    buf + basec * 16);
            gload16(Bt + (size_t)(n0 + row) * K + kk + ((cc ^ (row & 7)) << 3),
                    buf + 32768 + basec * 16);
        }
    };

    const int nt = K >> 6;
    STAGE(0, lds[0]);
    __syncthreads();
    int cur = 0;
    for (int t = 0; t < nt; ++t) {
        if (t + 1 < nt) STAGE((t + 1) << 6, lds[cur ^ 1]);
        const char* Ab = lds[cur];
        const char* Bb = lds[cur] + 32768;
#pragma unroll
        for (int hh = 0; hh < 2; ++hh) {
            s16x8 af[4], bfr[8];
#pragma unroll
            for (int mi = 0; mi < 4; ++mi) {
                int r = wr * 64 + mi * 16 + li;
                af[mi] = *(const s16x8*)(Ab + r * 128 + (((hh * 4 + lg) ^ (r & 7)) << 4));
            }
#pragma unroll
            for (int nj = 0; nj < 8; ++nj) {
                int r = wc * 128 + nj * 16 + li;
                bfr[nj] = *(const s16x8*)(Bb + r * 128 + (((hh * 4 + lg) ^ (r & 7)) << 4));
            }
#pragma unroll
            for (int mi = 0; mi < 4; ++mi)
#pragma unroll
                for (int nj = 0; nj < 8; ++nj)
                    acc[mi][nj] = __builtin_amdgcn_mfma_f32_16x16x32_bf16(
                        af[mi], bfr[nj], acc[mi][nj], 0, 0, 0);
        }
        __syncthreads();
        cur ^= 1;
    }

#pragma unroll
    for (int nj = 0; nj < 8; ++nj) {
        int col = n0 + wc * 128 + nj * 16 + li;
        float bv = bias[col];
#pragma unroll
        for (int mi = 0; mi < 4; ++mi) {
#pragma unroll
            for (int rg = 0; rg < 4; ++rg) {
                int grow = m0 + wr * 64 + mi * 16 + 4 * lg + rg;
                float v = acc[mi][nj][rg] + bv;
                float u = 0.7978845608028654f * v * (1.f + 0.044715f * v * v);
                u = fminf(fmaxf(u, -15.f), 15.f);
                float e = __expf(2.f * u);
                float th = (e - 1.f) / (e + 1.f);
                out[(size_t)grow * (size_t)Nn + col] = f2bf(0.5f * v * (1.f + th));
            }
        }
    }
}

// ---------------- flash attention: 4 warps x 32 q-rows, 32x32 MFMA, swapped -------
__global__ __launch_bounds__(256) void attn2(const u16* __restrict__ q,
                                             const u16* __restrict__ k,
                                             const u16* __restrict__ vt,
                                             u16* __restrict__ o) {
    __shared__ __align__(16) char qs[16384];
    __shared__ __align__(16) char kv[2][16384];
    const int tid = threadIdx.x, w = tid >> 6, lane = tid & 63;
    const int l31 = lane & 31, hi = lane >> 5;
    const int flat = blockIdx.x;
    const int wgs = (flat & 7) * 64 + (flat >> 3);
    const int bh = wgs >> 3, qt = wgs & 7;
    const size_t base = (size_t)bh * (N_ * DH_);
    const int q0 = qt * 128;

#pragma unroll
    for (int j = 0; j < 4; ++j) {
        int basec = j * 256 + w * 64;
        int idx = basec + lane;
        int row = idx >> 3, cc = idx & 7;
        gload16(q + base + (size_t)(q0 + row) * DH_ + ((cc ^ (row & 7)) << 3),
                qs + basec * 16);
    }
    auto STAGEKV = [&](int t, char* buf) {
#pragma unroll
        for (int j = 0; j < 4; ++j) {
            int basec = j * 256 + w * 64;
            int idx = basec + lane;
            if (idx < 512) {
                int row = idx >> 3, cc = idx & 7;
                gload16(k + base + (size_t)(t * 64 + row) * DH_ + ((cc ^ (row & 7)) << 3),
                        buf + basec * 16);
            } else {
                int i2 = idx - 512;
                int row = i2 >> 3, cc = i2 & 7;
                gload16(vt + base + (size_t)row * N_ + t * 64 + ((cc ^ (row & 7)) << 3),
                        buf + basec * 16);
            }
        }
    };
    STAGEKV(0, kv[0]);
    __syncthreads();

    s16x8 qf[4];
    const int qr = w * 32 + l31;
#pragma unroll
    for (int st = 0; st < 4; ++st)
        qf[st] = *(const s16x8*)(qs + qr * 128 + (((st * 2 + hi) ^ (qr & 7)) << 4));

    f32x16 oa[2];
#pragma unroll
    for (int r = 0; r < 16; ++r) { oa[0][r] = 0.f; oa[1][r] = 0.f; }
    float mrow = -3e38f, lrow = 0.f;
    const float CSC = 0.125f * 1.44269504088896f;

    int cur = 0;
    for (int t = 0; t < 16; ++t) {
        if (t + 1 < 16) STAGEKV(t + 1, kv[cur ^ 1]);
        const char* Kb = kv[cur];
        const char* Vb = kv[cur] + 8192;

        f32x16 s[2];
#pragma unroll
        for (int r = 0; r < 16; ++r) { s[0][r] = 0.f; s[1][r] = 0.f; }
#pragma unroll
        for (int st = 0; st < 4; ++st) {
#pragma unroll
            for (int ks = 0; ks < 2; ++ks) {
                int r = ks * 32 + l31;
                s16x8 ka = *(const s16x8*)(Kb + r * 128 + (((st * 2 + hi) ^ (r & 7)) << 4));
                s[ks] = __builtin_amdgcn_mfma_f32_32x32x16_bf16(ka, qf[st], s[ks], 0, 0, 0);
            }
        }

        float tmax = s[0][0];
#pragma unroll
        for (int r = 1; r < 16; ++r) tmax = fmaxf(tmax, s[0][r]);
#pragma unroll
        for (int r = 0; r < 16; ++r) tmax = fmaxf(tmax, s[1][r]);
        tmax = fmaxf(tmax, __shfl_xor(tmax, 32));
        float mn = fmaxf(mrow, tmax);
        float al = __builtin_amdgcn_exp2f((mrow - mn) * CSC);
        float nmc = -mn * CSC;
        float rs0 = 0.f, rs1 = 0.f;
#pragma unroll
        for (int r = 0; r < 16; ++r) {
            float p0 = __builtin_amdgcn_exp2f(fmaf(s[0][r], CSC, nmc));
            float p1 = __builtin_amdgcn_exp2f(fmaf(s[1][r], CSC, nmc));
            s[0][r] = p0; s[1][r] = p1;
            rs0 += p0; rs1 += p1;
        }
        float rs = rs0 + rs1;
        rs += __shfl_xor(rs, 32);
        lrow = lrow * al + rs;
        mrow = mn;
#pragma unroll
        for (int r = 0; r < 16; ++r) { oa[0][r] *= al; oa[1][r] *= al; }

        unsigned u[16];
#pragma unroll
        for (int ks = 0; ks < 2; ++ks)
#pragma unroll
            for (int j = 0; j < 4; ++j) {
                u[ks * 8 + 2 * j]     = cvtpk(s[ks][4 * j + 0], s[ks][4 * j + 1]);
                u[ks * 8 + 2 * j + 1] = cvtpk(s[ks][4 * j + 2], s[ks][4 * j + 3]);
            }

#pragma unroll
        for (int kstep = 0; kstep < 4; ++kstep) {
            unsigned b0 = u[kstep * 4 + 0], b1 = u[kstep * 4 + 1];
            unsigned b2 = u[kstep * 4 + 2], b3 = u[kstep * 4 + 3];
            asm volatile("v_permlane32_swap_b32 %0, %1" : "+v"(b0), "+v"(b2));
            asm volatile("v_permlane32_swap_b32 %0, %1" : "+v"(b1), "+v"(b3));
            u32x4 pbu = (u32x4){b0, b1, b2, b3};
            s16x8 pb = __builtin_bit_cast(s16x8, pbu);
#pragma unroll
            for (int ds = 0; ds < 2; ++ds) {
                int r = ds * 32 + l31;
                s16x8 va = *(const s16x8*)(Vb + r * 128 + (((kstep * 2 + hi) ^ (r & 7)) << 4));
                oa[ds] = __builtin_amdgcn_mfma_f32_32x32x16_bf16(va, pb, oa[ds], 0, 0, 0);
            }
        }
        __syncthreads();
        cur ^= 1;
    }

    float inv = 1.f / lrow;
#pragma unroll
    for (int ds = 0; ds < 2; ++ds)
#pragma unroll
        for (int j = 0; j < 4; ++j)
#pragma unroll
            for (int t2 = 0; t2 < 2; ++t2) {
                unsigned pk = cvtpk(oa[ds][4 * j + 2 * t2] * inv,
                                    oa[ds][4 * j + 2 * t2 + 1] * inv);
                int row = qr;
                int dch = 4 * ds + j;
                *(unsigned*)(qs + row * 128 + ((dch ^ (row & 7)) << 4) +
                             (4 * hi + 2 * t2) * 2) = pk;
            }
    __syncthreads();
    {
        int r = tid >> 1, h2 = tid & 1;
        const int b = bh >> 4, hd = bh & 15;
        size_t obase = ((size_t)(b * N_ + q0 + r)) * D_ + hd * DH_;
#pragma unroll
        for (int c = 0; c < 4; ++c) {
            int c2 = h2 * 4 + c;
            s16x8 v = *(const s16x8*)(qs + r * 128 + ((c2 ^ (r & 7)) << 4));
            *(s16x8*)(o + obase + c2 * 8) = v;
        }
    }
}

// ---------------------------------------------------------------------------------
extern "C" void kernel_launch(void* const* d_in, const int* in_sizes, int n_in,
                              void* d_out, int out_size, void* d_ws, size_t ws_size,
                              hipStream_t stream) {
    const float* x    = (const float*)d_in[0];
    const float* c    = (const float*)d_in[1];
    const float* Wq   = (const float*)d_in[2];
    const float* bq   = (const float*)d_in[3];
    const float* Wkv  = (const float*)d_in[4];
    const float* bkv  = (const float*)d_in[5];
    const float* Wo   = (const float*)d_in[6];
    const float* bo   = (const float*)d_in[7];
    const float* W1   = (const float*)d_in[8];
    const float* b1   = (const float*)d_in[9];
    const float* W2   = (const float*)d_in[10];
    const float* b2   = (const float*)d_in[11];
    const float* Wada = (const float*)d_in[12];
    const float* bada = (const float*)d_in[13];

    char* ws = (char*)d_ws;
    const size_t MB = 1024 * 1024;
    u16*   wqkvT = (u16*)(ws + 0);       // 6MB
    u16*   woT  = (u16*)(ws + 6 * MB);   // 2MB
    u16*   w1T  = (u16*)(ws + 8 * MB);   // 8MB
    u16*   w2T  = (u16*)(ws + 16 * MB);  // 8MB
    float* mod  = (float*)(ws + 24 * MB);            // 96KB
    float* modp = (float*)(ws + 24 * MB + 131072);   // 768KB partials
    u16*   h    = (u16*)(ws + 25 * MB);  // 8MB
    u16*   qb   = (u16*)(ws + 33 * MB);  // 24MB: q | k(+4M elems) | vt(+8M elems)
    u16*   ao   = (u16*)(ws + 57 * MB);  // 8MB
    float* x1   = (float*)(ws + 65 * MB);// 16MB
    u16*   m1   = (u16*)(ws + 33 * MB);  // 32MB, reuses qkv+ao (dead by then)
    float* outp = (float*)d_out;

    prep_all<<<3840, 256, 0, stream>>>(Wq, Wkv, Wo, W1, W2, c, Wada,
                                       wqkvT, woT, w1T, w2T, modp);
    reduce_mod<<<dim3(24, 4), 256, 0, stream>>>(modp, bada, mod);

    ln_mod<<<M_, 256, 0, stream>>>(x, mod, 0, 1, h);

    gemm_qkv<<<dim3(24, 32), 512, 0, stream>>>(h, wqkvT, bq, bkv, qb, M_, 3 * D_, D_);

    attn2<<<512, 256, 0, stream>>>(qb, qb + 4194304, qb + 8388608, ao);

    gemm_bt<2><<<dim3(8, 32), 512, 0, stream>>>(ao, woT, bo, x1, x, mod, M_, D_, D_, 2);

    ln_mod<<<M_, 256, 0, stream>>>(x1, mod, 3, 4, h);

    gemm256_gelu<<<256, 512, 0, stream>>>(h, w1T, b1, m1, M_, 4 * D_, D_);
    gemm_bt<4><<<dim3(8, 32), 512, 0, stream>>>(m1, w2T, b2, outp, x1, mod, M_, D_, 4 * D_, 5);
}